// Round 4
// baseline (122.712 us; speedup 1.0000x reference)
//
#include <hip/hip_runtime.h>
#include <hip/hip_fp16.h>

#define NN 100000
#define NE 625000
#define ND 128
#define NR 16
#define SLOPE 0.2f
#define PAD 132          // floats per LDS x-row (128+4): conflict-free ds_read_b128
#define CHUNK 512        // edges per block-chunk in binned passes
#define CHUNKS_PER_REL 80

// ---------- helpers ----------
__device__ __forceinline__ unsigned align16u(unsigned v) { return (v + 15u) & ~15u; }

// padded prefix offset of bin r (bins 16-aligned so int2/float2 stay 8B-aligned)
__device__ __forceinline__ unsigned bin_off(const unsigned* __restrict__ relCount, int r) {
    unsigned acc = 0;
#pragma unroll
    for (int i = 0; i < NR; ++i) { unsigned c = align16u(relCount[i]); if (i < r) acc += c; }
    return acc;
}

// K0: zero the 32 counters (relCount[16] | relCursor[16])
__global__ void zero_counters(unsigned* __restrict__ c) {
    if (threadIdx.x < 32) c[threadIdx.x] = 0u;
}

// K1: precompute planar fp16 table + zero segsum + per-rel histogram.
// table plane r       : U_r[n] = dot(a[r][0:128],   x[n])
// table plane 16+r    : V_r[n] = dot(a[r][128:256], x[n])
// Block = 4 waves, 64 nodes; wave q computes 8 outputs/node (scalar K$ A-loads).
__global__ __launch_bounds__(256) void precompute_table(
        const float* __restrict__ x, const float* __restrict__ a,
        const int* __restrict__ etype,
        __half* __restrict__ table, float* __restrict__ segsum,
        unsigned* __restrict__ relCount) {
    __shared__ float xs[64 * PAD];          // 33,792 B
    __shared__ unsigned hist[NR];

    int tid = threadIdx.x;
    int blockBase = blockIdx.x * 64;

    if (tid < NR) hist[tid] = 0u;

    // stage 64 node rows coalesced
#pragma unroll
    for (int i = 0; i < 8; ++i) {
        int f = tid + i * 256;
        int row = f >> 5;
        int col = (f & 31) << 2;
        size_t g = (size_t)blockBase * ND + (size_t)f * 4;
        float4 v = (g < (size_t)NN * ND) ? *(const float4*)&x[g]
                                         : make_float4(0.f, 0.f, 0.f, 0.f);
        *(float4*)&xs[row * PAD + col] = v;
    }
    __syncthreads();

    // histogram slice: 400 edges per block (1563 * 400 >= NE)
    {
        int base = blockIdx.x * 400;
        int cnt = NE - base; if (cnt > 400) cnt = 400;
        for (int i = tid; i < cnt; i += 256)
            atomicAdd(&hist[etype[base + i]], 1u);
    }
    __syncthreads();
    if (tid < NR) atomicAdd(&relCount[tid], hist[tid]);

    int q  = __builtin_amdgcn_readfirstlane(tid >> 6);
    int nl = tid & 63;
    int n  = blockBase + nl;
    if (n >= NN) return;
    if (q == 0) segsum[n] = 0.0f;

    const float* arow = a + (size_t)((q & 1) * 8) * 256 + (q >> 1) * 128;
    float acc[8];
#pragma unroll
    for (int j = 0; j < 8; ++j) acc[j] = 0.0f;

    const float* xr = &xs[nl * PAD];
    for (int k = 0; k < ND; k += 4) {
        float4 xv = *(const float4*)&xr[k];
#pragma unroll
        for (int j = 0; j < 8; ++j) {
            float4 av = *(const float4*)&arow[(size_t)j * 256 + k];   // s_load
            acc[j] += av.x * xv.x + av.y * xv.y + av.z * xv.z + av.w * xv.w;
        }
    }
#pragma unroll
    for (int j = 0; j < 8; ++j) {
        int rj = (q & 1) * 8 + j;
        int plane = ((q >> 1) << 4) + rj;     // 0..15 = U, 16..31 = V
        table[(size_t)plane * NN + n] = __float2half_rn(acc[j]);
    }
}

// K2: bin edges by rel. Per-block LDS ranks + one global cursor reservation per rel.
__global__ __launch_bounds__(256) void scatter_edges(
        const int* __restrict__ srcs, const int* __restrict__ dsts,
        const int* __restrict__ etype,
        const unsigned* __restrict__ relCount, unsigned* __restrict__ relCursor,
        int* __restrict__ bs, int* __restrict__ bd, int* __restrict__ beid) {
    __shared__ unsigned hist[NR];
    __shared__ unsigned basep[NR];
    int t = threadIdx.x;
    if (t < NR) hist[t] = 0u;
    __syncthreads();

    int e0 = blockIdx.x * CHUNK + t * 2;
    int r0 = -1, r1 = -1; unsigned k0 = 0, k1 = 0;
    int s0 = 0, s1 = 0, d0 = 0, d1 = 0;
    if (e0 < NE) {
        s0 = srcs[e0]; d0 = dsts[e0]; r0 = etype[e0];
        k0 = atomicAdd(&hist[r0], 1u);
        if (e0 + 1 < NE) {
            s1 = srcs[e0 + 1]; d1 = dsts[e0 + 1]; r1 = etype[e0 + 1];
            k1 = atomicAdd(&hist[r1], 1u);
        }
    }
    __syncthreads();
    if (t < NR) basep[t] = (hist[t] > 0u) ? atomicAdd(&relCursor[t], hist[t]) : 0u;
    __syncthreads();

    if (r0 >= 0) {
        unsigned p = bin_off(relCount, r0) + basep[r0] + k0;
        bs[p] = s0; bd[p] = d0; beid[p] = e0;
    }
    if (r1 >= 0) {
        unsigned p = bin_off(relCount, r1) + basep[r1] + k1;
        bs[p] = s1; bd[p] = d1; beid[p] = e0 + 1;
    }
}

// Map block -> (rel, chunk) so blocks of rel r land on XCD r/2 (blockIdx % 8 round-robin).
__device__ __forceinline__ void block_rel_chunk(int b, int* r, int* c) {
    *r = 2 * (b & 7) + ((b >> 3) & 1);
    *c = b >> 4;
}

// K3: binned edge pass. u = U_r[src], v = V_r[dst] (L2-resident 800 KB/XCD slabs),
// ex = exp(lrelu(u+v)); write ex in-place over bd (int-typed stores to keep
// the load->store dependency); atomic segment-sum.
__global__ __launch_bounds__(256) void edge_ab_binned(
        const int* __restrict__ bs, int* __restrict__ bdx,
        const unsigned* __restrict__ relCount,
        const __half* __restrict__ table, float* __restrict__ segsum) {
    int r, c0; block_rel_chunk(blockIdx.x, &r, &c0);
    unsigned off = bin_off(relCount, r);
    unsigned end = off + relCount[r];
    const __half* Tu = table + (size_t)r * NN;
    const __half* Tv = table + (size_t)(NR + r) * NN;

    for (unsigned i0 = off + (unsigned)c0 * CHUNK; i0 < end;
         i0 += (unsigned)CHUNKS_PER_REL * CHUNK) {
        unsigned i = i0 + threadIdx.x * 2u;
        if (i >= end) continue;
        int2 s2 = *(const int2*)&bs[i];
        int2 d2 = *(const int2*)&bdx[i];
        bool two = (i + 1u < end);
        float u0 = __half2float(Tu[s2.x]);
        float v0 = __half2float(Tv[d2.x]);
        float a0 = u0 + v0; a0 = (a0 >= 0.f) ? a0 : SLOPE * a0;
        float ex0 = __expf(a0);
        if (two) {
            float u1 = __half2float(Tu[s2.y]);
            float v1 = __half2float(Tv[d2.y]);
            float a1 = u1 + v1; a1 = (a1 >= 0.f) ? a1 : SLOPE * a1;
            float ex1 = __expf(a1);
            *(int2*)&bdx[i] = make_int2(__float_as_int(ex0), __float_as_int(ex1));
            atomicAdd(&segsum[s2.x], ex0);
            atomicAdd(&segsum[s2.y], ex1);
        } else {
            bdx[i] = __float_as_int(ex0);
            atomicAdd(&segsum[s2.x], ex0);
        }
    }
}

// K4: alpha = ex / segsum[src]; scatter to out[orig_edge]. Same bin walk.
__global__ __launch_bounds__(256) void edge_c_binned(
        const int* __restrict__ bs, const int* __restrict__ bexi,
        const int* __restrict__ beid,
        const unsigned* __restrict__ relCount,
        const float* __restrict__ segsum, float* __restrict__ out) {
    int r, c0; block_rel_chunk(blockIdx.x, &r, &c0);
    unsigned off = bin_off(relCount, r);
    unsigned end = off + relCount[r];

    for (unsigned i0 = off + (unsigned)c0 * CHUNK; i0 < end;
         i0 += (unsigned)CHUNKS_PER_REL * CHUNK) {
        unsigned i = i0 + threadIdx.x * 2u;
        if (i >= end) continue;
        int2 s2 = *(const int2*)&bs[i];
        int2 ex2 = *(const int2*)&bexi[i];
        int2 id2 = *(const int2*)&beid[i];
        bool two = (i + 1u < end);
        out[id2.x] = __fdividef(__int_as_float(ex2.x), segsum[s2.x]);
        if (two)
            out[id2.y] = __fdividef(__int_as_float(ex2.y), segsum[s2.y]);
    }
}

extern "C" void kernel_launch(void* const* d_in, const int* in_sizes, int n_in,
                              void* d_out, int out_size, void* d_ws, size_t ws_size,
                              hipStream_t stream) {
    const float* x     = (const float*)d_in[0];
    const float* a     = (const float*)d_in[1];
    const int*   eidx  = (const int*)d_in[2];
    const int*   etype = (const int*)d_in[3];
    const int*   srcs  = eidx;
    const int*   dsts  = eidx + NE;
    float*       out   = (float*)d_out;

    // ws layout (bytes, all 16-aligned). Binned arrays padded: NE + 16*NR slots.
    const size_t BINSZ = (size_t)(NE + 16 * NR) * 4;       // 2,501,024
    char* ws = (char*)d_ws;
    __half*   table   = (__half*)(ws);                      // 6,400,000
    int*      bs      = (int*)(ws + 6400000);
    int*      bdx     = (int*)(ws + 6400000 + BINSZ);
    int*      beid    = (int*)(ws + 6400000 + 2 * BINSZ);
    float*    segsum  = (float*)(ws + 6400000 + 3 * BINSZ); //   400,000
    unsigned* counters= (unsigned*)(ws + 6400000 + 3 * BINSZ + 400000); // 128 B
    unsigned* relCount  = counters;
    unsigned* relCursor = counters + NR;

    dim3 blk(256);
    dim3 pgrid((NN + 63) / 64);                 // 1563
    dim3 sgrid((NE + CHUNK - 1) / CHUNK);       // 1221
    dim3 bgrid(NR * CHUNKS_PER_REL);            // 1280

    zero_counters<<<dim3(1), dim3(64), 0, stream>>>(counters);
    precompute_table<<<pgrid, blk, 0, stream>>>(x, a, etype, table, segsum, relCount);
    scatter_edges<<<sgrid, blk, 0, stream>>>(srcs, dsts, etype, relCount, relCursor,
                                             bs, bdx, beid);
    edge_ab_binned<<<bgrid, blk, 0, stream>>>(bs, bdx, relCount, table, segsum);
    edge_c_binned<<<bgrid, blk, 0, stream>>>(bs, bdx, beid, relCount, segsum, out);
}

// Round 5
// 75.837 us; speedup vs baseline: 1.6181x; 1.6181x over previous
//
#include <hip/hip_runtime.h>
#include <hip/hip_fp16.h>

#define NN 100000
#define NE 625000
#define ND 128
#define NR 16
#define SLOPE 0.2f
#define PAD 132   // floats per LDS x-row: 128+4 pad (16B aligned, conflict-free b128)

// K1: precompute fp16 table, interleaved layout: table[n*32 + o]
//   o in [0,16)  : U_o(n) = dot(a[o][0:128],   x[n])
//   o in [16,32) : V_{o-16}(n) = dot(a[o-16][128:256], x[n])
// One 64 B line per node. Block = 4 waves / 64 nodes; wave q computes outputs
// q*8..q*8+7 for all 64 nodes -> A-row address wave-uniform -> scalar K$ loads.
// x staged coalesced into padded LDS. segsum init fused.
__global__ __launch_bounds__(256) void precompute_table(
        const float* __restrict__ x, const float* __restrict__ a,
        __half* __restrict__ table, float* __restrict__ segsum) {
    __shared__ float xs[64 * PAD];          // 33,792 B

    int tid = threadIdx.x;
    int blockBase = blockIdx.x * 64;

    // stage 64 node rows (32 KB) fully coalesced
#pragma unroll
    for (int i = 0; i < 8; ++i) {
        int f = tid + i * 256;              // float4 slot in tile [0,2048)
        int row = f >> 5;
        int col = (f & 31) << 2;
        size_t g = (size_t)blockBase * ND + (size_t)f * 4;
        float4 v = (g < (size_t)NN * ND) ? *(const float4*)&x[g]
                                         : make_float4(0.f, 0.f, 0.f, 0.f);
        *(float4*)&xs[row * PAD + col] = v;
    }
    __syncthreads();

    int q  = __builtin_amdgcn_readfirstlane(tid >> 6);  // wave id, uniform
    int nl = tid & 63;
    int n  = blockBase + nl;
    if (n >= NN) return;
    if (q == 0) segsum[n] = 0.0f;

    const float* arow = a + (size_t)((q & 1) * 8) * 256 + (q >> 1) * 128;
    float acc[8];
#pragma unroll
    for (int j = 0; j < 8; ++j) acc[j] = 0.0f;

    const float* xr = &xs[nl * PAD];
    for (int k = 0; k < ND; k += 4) {
        float4 xv = *(const float4*)&xr[k];
#pragma unroll
        for (int j = 0; j < 8; ++j) {
            float4 av = *(const float4*)&arow[(size_t)j * 256 + k];   // s_load
            acc[j] += av.x * xv.x + av.y * xv.y + av.z * xv.z + av.w * xv.w;
        }
    }

    __half2 hv[4];
#pragma unroll
    for (int p = 0; p < 4; ++p)
        hv[p] = __floats2half2_rn(acc[p * 2], acc[p * 2 + 1]);
    *(uint4*)(table + (size_t)n * 32 + q * 8) = *(uint4*)hv;
}

// agent-scope (device-coherent) 4 B load -> bypasses the non-coherent L1
__device__ __forceinline__ unsigned ld_agent_u32(const unsigned* p) {
    return __hip_atomic_load((unsigned*)p, __ATOMIC_RELAXED, __HIP_MEMORY_SCOPE_AGENT);
}
__device__ __forceinline__ float tbl_gather(const unsigned* tbl, unsigned halfIdx) {
    unsigned w = ld_agent_u32(&tbl[halfIdx >> 1]);
    unsigned short h = (unsigned short)((halfIdx & 1u) ? (w >> 16) : w);
    return __half2float(__ushort_as_half(h));
}

// K2: 4 edges/thread. e = U[src][r] + V[dst][r]; leaky-relu; exp (softmax is
// shift-invariant, |e| < ~12 so no max pass); store ex; atomic segment-sum.
__global__ __launch_bounds__(256) void edge_ab(
        const int* __restrict__ srcs, const int* __restrict__ dsts,
        const int* __restrict__ etype, const unsigned* __restrict__ tbl,
        float* __restrict__ ex_buf, float* __restrict__ segsum) {
    int t = blockIdx.x * blockDim.x + threadIdx.x;
    int e = t * 4;
    if (e >= NE) return;   // NE % 4 == 0 -> no partial tail
    int4 s4 = *(const int4*)&srcs[e];
    int4 d4 = *(const int4*)&dsts[e];
    int4 r4 = *(const int4*)&etype[e];
    int s[4] = {s4.x, s4.y, s4.z, s4.w};
    int d[4] = {d4.x, d4.y, d4.z, d4.w};
    int r[4] = {r4.x, r4.y, r4.z, r4.w};

    // 8 independent L1-bypassed gathers in flight
    float u[4], v[4];
#pragma unroll
    for (int j = 0; j < 4; ++j)
        u[j] = tbl_gather(tbl, (unsigned)s[j] * 32u + (unsigned)r[j]);
#pragma unroll
    for (int j = 0; j < 4; ++j)
        v[j] = tbl_gather(tbl, (unsigned)d[j] * 32u + 16u + (unsigned)r[j]);

    float ex[4];
#pragma unroll
    for (int j = 0; j < 4; ++j) {
        float av = u[j] + v[j];
        av = (av >= 0.f) ? av : SLOPE * av;
        ex[j] = __expf(av);
    }
    float4 exv; exv.x = ex[0]; exv.y = ex[1]; exv.z = ex[2]; exv.w = ex[3];
    *(float4*)&ex_buf[e] = exv;
#pragma unroll
    for (int j = 0; j < 4; ++j)
        atomicAdd(&segsum[s[j]], ex[j]);
}

// K3: alpha = ex / segsum[src], 4 edges/thread (segsum = 400 KB, L2-resident)
__global__ __launch_bounds__(256) void edge_c(
        const int* __restrict__ srcs, const float* __restrict__ ex_buf,
        const float* __restrict__ segsum, float* __restrict__ out) {
    int t = blockIdx.x * blockDim.x + threadIdx.x;
    int e = t * 4;
    if (e >= NE) return;
    int4 s4 = *(const int4*)&srcs[e];
    float4 ex = *(const float4*)&ex_buf[e];
    float ss0 = segsum[s4.x];
    float ss1 = segsum[s4.y];
    float ss2 = segsum[s4.z];
    float ss3 = segsum[s4.w];
    float4 o;
    o.x = __fdividef(ex.x, ss0);
    o.y = __fdividef(ex.y, ss1);
    o.z = __fdividef(ex.z, ss2);
    o.w = __fdividef(ex.w, ss3);
    *(float4*)&out[e] = o;
}

extern "C" void kernel_launch(void* const* d_in, const int* in_sizes, int n_in,
                              void* d_out, int out_size, void* d_ws, size_t ws_size,
                              hipStream_t stream) {
    const float* x     = (const float*)d_in[0];           // [NN, 128]
    const float* a     = (const float*)d_in[1];           // [16, 256]
    const int*   eidx  = (const int*)d_in[2];             // [2, NE]
    const int*   etype = (const int*)d_in[3];             // [NE]
    const int*   srcs  = eidx;
    const int*   dsts  = eidx + NE;
    float*       out   = (float*)d_out;

    char* ws = (char*)d_ws;
    __half* table  = (__half*)(ws);                        // 6,400,000 B
    float*  ex_buf = (float*)(ws + 6400000);               // 2,500,000 B
    float*  segsum = (float*)(ws + 8900000);               //   400,000 B

    dim3 blk(256);
    dim3 pgrid((NN + 63) / 64);                            // 1563
    dim3 egrid((NE / 4 + 255) / 256);                      // 611

    precompute_table<<<pgrid, blk, 0, stream>>>(x, a, table, segsum);
    edge_ab<<<egrid, blk, 0, stream>>>(srcs, dsts, etype, (const unsigned*)table,
                                       ex_buf, segsum);
    edge_c<<<egrid, blk, 0, stream>>>(srcs, ex_buf, segsum, out);
}